// Round 4
// baseline (154.094 us; speedup 1.0000x reference)
//
#include <hip/hip_runtime.h>
#include <hip/hip_bf16.h>
#include <hip/hip_fp8.h>

// TextualContrastiveLoss: B=4096, D=1024, NUM_CLASSES=100, T=0.5
//   z = l2norm(emb); reps = [z_i; z_j] (8192x1024)
//   sim = reps @ reps^T; e = exp(sim/T) with diag excluded
//   loss = mean_n( log(sum_m e) - log(sum_{m: lab match} e) )
//
// R11 MX mfma_scale_32x32x64 fp8: 71. R12 raw s_barrier+vmcnt: 63.5.
// R15: XCD remap. R16: MX-FP4. R17: deterministic parts stores.
// R18: spill-free fused D/N butterfly epilogue, undef-high fp4 ops,
//      raw v_exp_f32, setprio: gemm 44.8us (champion K-loop).
// R19 FAILED: 3-buffer single-barrier pipeline: 48KB LDS -> 3 blocks/CU
//      (was 4) -> gemm 60.5. TLP > prefetch depth for this kernel.
//      K-loop reverted to R18 exactly.
// R20: total(124) = fill(45, harness) + norm(7) + gemm(45) + fin(2)
//      + ~24us launch gaps. Attack the gaps: fuse finalize into gemm
//      via last-block atomic counter. All cross-block data written via
//      DEVICE-SCOPE ATOMICS (coherence-point ops, never dirty in
//      per-XCD L2) => no wbl2 fence needed (avoids the R14 trap).
//      Epilogue returns to direct global atomicAdd (R0-proven) into
//      float2 nomden; __syncthreads drains vmcnt; one ACQ_REL counter
//      inc; last block does the 64KB log-reduce with agent loads.

#define BHALF 4096
#define N2 8192
#define DK 1024               // elements per row
#define DKB 512               // fp4: bytes per row
#define TILE 128
#define BKB 64                // K bytes staged per kt = 128 elems (8 kt)
#define NTILE 64              // 8192/128
#define NBLK 2080             // 64*65/2 upper-tri tiles = 8 * 260

typedef __attribute__((ext_vector_type(16))) float f32x16;
typedef __attribute__((ext_vector_type(4))) int v4i;
typedef __attribute__((ext_vector_type(8))) int v8i;
typedef unsigned char u8;
typedef unsigned short u16;

// exp(s/0.5) with q = 32*z: sim = acc/1024 -> exp2(acc * 2*log2(e)/1024)
#define EXP_SCALE4 0.0028177637517362566f
#define UNIT_SCALE 0x7f7f7f7f    // E8M0 127 = 2^0 in every byte

// raw barrier / waitcnt — no compiler-inserted vmcnt(0) drain
#define WAITVM(n) asm volatile("s_waitcnt vmcnt(" #n ")" ::: "memory")
#define BAR()     asm volatile("s_barrier" ::: "memory")

// bare v_exp_f32 (2^x); input range here is [-2.9, 2.9] so no denormal
// fixup needed. s_nop covers the TRANS->VALU hazard across the asm edge.
static __device__ __forceinline__ float fexp2(float x) {
    float r;
    asm("v_exp_f32 %0, %1\n\ts_nop 1" : "=v"(r) : "v"(x));
    return r;
}

// float -> fp4 e2m1 nibble, RNE on the e2m1 grid {0,.5,1,1.5,2,3,4,6}
static __device__ __forceinline__ unsigned nib4(float x) {
    unsigned s = (__builtin_bit_cast(unsigned, x) >> 31) << 3;
    float a = fminf(fabsf(x), 6.0f);
    unsigned c;
    if (a < 2.0f)      c = (unsigned)lrintf(a * 2.0f);      // 0,.5..2
    else if (a < 4.0f) c = (unsigned)lrintf(a) + 2u;        // 2,3,4
    else               c = (a < 5.0f) ? 6u : 7u;            // 4 / 6
    return s | c;
}

__global__ __launch_bounds__(256) void normalize_kernel(
    const float* __restrict__ emb_i, const float* __restrict__ emb_j,
    u16* __restrict__ reps, float* __restrict__ nomden,
    unsigned* __restrict__ counter, float* __restrict__ out) {
    // one wave per row: 2048 blocks x 4 waves; 16 floats/lane
    int idx = blockIdx.x * 256 + threadIdx.x;
    if (idx < 2 * N2) nomden[idx] = 0.0f;            // zero nom+den pairs
    if (idx == 0) { out[0] = 0.0f; counter[0] = 0u; }
    int r = blockIdx.x * 4 + (threadIdx.x >> 6);     // 0..8191
    int lane = threadIdx.x & 63;
    const float* src = (r < BHALF) ? (emb_i + (size_t)r * DK)
                                   : (emb_j + (size_t)(r - BHALF) * DK);
    const float4* srcv = (const float4*)src;         // 256 float4 per row
    float4 v[4];
    float s = 0.f;
#pragma unroll
    for (int k = 0; k < 4; ++k) {
        v[k] = srcv[k * 64 + lane];
        s += v[k].x * v[k].x + v[k].y * v[k].y +
             v[k].z * v[k].z + v[k].w * v[k].w;
    }
#pragma unroll
    for (int m = 1; m <= 32; m <<= 1) s += __shfl_xor(s, m, 64);
    float scale = 32.0f / fmaxf(sqrtf(s), 1e-12f);   // q = 32 * z
    u16* dst = reps + (size_t)r * 256;               // 256 u16 per row
#pragma unroll
    for (int k = 0; k < 4; ++k) {
        unsigned p = nib4(v[k].x * scale) |
                     (nib4(v[k].y * scale) << 4) |
                     (nib4(v[k].z * scale) << 8) |
                     (nib4(v[k].w * scale) << 12);
        dst[k * 64 + lane] = (u16)p;                 // even elem = low nibble
    }
}

__global__ __launch_bounds__(256, 4) void gemm_loss_kernel(
    const u8* __restrict__ reps, const int* __restrict__ labels,
    float2* __restrict__ nomden, unsigned* __restrict__ counter,
    float* __restrict__ out) {
    // Double-buffered fp4 tiles: 2 x (A 8KB + B 8KB) = 32 KB.
    // Staged rows are 64 B = 4 x 16B blocks = 128 elems. Swizzle: LDS
    // slot (row, b) holds global block b ^ swz(row), swz(r)=(r^(r>>2))&3.
    __shared__ __align__(16) u8 A_s[2][TILE * BKB];
    __shared__ __align__(16) u8 B_s[2][TILE * BKB];

    // XCD-contiguous remap (R15): each mod-8 class walks 260 contiguous
    // tri-indices for L2 reuse.
    int g = blockIdx.x;
    int rem = (g & 7) * 260 + (g >> 3);
    int bi = 0;
    while (rem >= NTILE - bi) { rem -= NTILE - bi; ++bi; }
    int bj = bi + rem;
    int rowBase = bi * TILE;
    int colBase = bj * TILE;

    int tid = threadIdx.x;
    int w = tid >> 6;             // wave 0..3 -> 2x2 of 64x64 subtiles
    int lane = tid & 63;
    int wm = w >> 1, wn = w & 1;
    int hk = lane >> 5;           // lane half: K-half within a 64-K MFMA
    int l31 = lane & 31;

    f32x16 acc[2][2];
#pragma unroll
    for (int i = 0; i < 2; ++i)
#pragma unroll
        for (int j = 0; j < 2; ++j)
#pragma unroll
            for (int r = 0; r < 16; ++r) acc[i][j][r] = 0.0f;

    // staging: 1KB chunk = 16 rows x 64 B; lane l -> LDS (row l>>2,
    // block l&3); fetches global block (l&3)^swz(srow)
    int srow = lane >> 2;
    int sbg = (lane & 3) ^ ((srow ^ (srow >> 2)) & 3);
    const u8* gA = reps + (size_t)(rowBase + w * 32 + srow) * DKB + sbg * 16;
    const u8* gB = reps + (size_t)(colBase + w * 32 + srow) * DKB + sbg * 16;

    // fragment reads: per kt the 64B row covers 128 elems = 2 MFMA
    // K-steps of 64; lane holds elems [ks*64+32*hk, +32) = 16 B at
    // global block (ks*2+hk) -> one b128 per fragment.
    int rswz = (l31 ^ (l31 >> 2)) & 3;
    unsigned aOff[2][2], bOff[2][2];   // [i][ks]
#pragma unroll
    for (int i = 0; i < 2; ++i) {
#pragma unroll
        for (int ks = 0; ks < 2; ++ks) {
            int ra = (wm * 64 + i * 32 + l31) * BKB;
            aOff[i][ks] = ra + (((ks * 2 + hk) ^ rswz) << 4);
            int rb = (wn * 64 + i * 32 + l31) * BKB;
            bOff[i][ks] = rb + (((ks * 2 + hk) ^ rswz) << 4);
        }
    }

#define STAGE(buf, kt)                                                       \
    {                                                                        \
        _Pragma("unroll")                                                    \
        for (int c = 0; c < 2; ++c) {                                        \
            int chunk = 2 * w + c;                                           \
            __builtin_amdgcn_global_load_lds(                                \
                (const __attribute__((address_space(1))) void*)              \
                    (gA + (size_t)c * 16 * DKB + (kt) * BKB),                \
                (__attribute__((address_space(3))) void*)                    \
                    &A_s[buf][chunk * 1024], 16, 0, 0);                      \
            __builtin_amdgcn_global_load_lds(                                \
                (const __attribute__((address_space(1))) void*)              \
                    (gB + (size_t)c * 16 * DKB + (kt) * BKB),                \
                (__attribute__((address_space(3))) void*)                    \
                    &B_s[buf][chunk * 1024], 16, 0, 0);                      \
        }                                                                    \
    }
    // Per kt: 2 K-steps x 4 MFMAs; fp4 fmt (cbsz=4, blgp=4) reads only
    // the LOW 4 regs of each 8-reg operand — leave the high half undef
    // (no v_mov duplication).
#define COMPUTE(buf)                                                         \
    {                                                                        \
        _Pragma("unroll")                                                    \
        for (int ks = 0; ks < 2; ++ks) {                                     \
            v8i aF[2], bF[2];                                                \
            _Pragma("unroll")                                                \
            for (int i = 0; i < 2; ++i) {                                    \
                v4i a4 = *(const v4i*)&A_s[buf][aOff[i][ks]];                \
                aF[i] = __builtin_shufflevector(a4, a4, 0,1,2,3,-1,-1,-1,-1);\
                v4i b4 = *(const v4i*)&B_s[buf][bOff[i][ks]];                \
                bF[i] = __builtin_shufflevector(b4, b4, 0,1,2,3,-1,-1,-1,-1);\
            }                                                                \
            __builtin_amdgcn_s_setprio(1);                                   \
            _Pragma("unroll")                                                \
            for (int i = 0; i < 2; ++i)                                      \
                _Pragma("unroll")                                            \
                for (int j = 0; j < 2; ++j)                                  \
                    acc[i][j] =                                              \
                        __builtin_amdgcn_mfma_scale_f32_32x32x64_f8f6f4(     \
                            aF[i], bF[j], acc[i][j], 4, 4,                   \
                            0, UNIT_SCALE, 0, UNIT_SCALE);                   \
            __builtin_amdgcn_s_setprio(0);                                   \
        }                                                                    \
    }

    // Pipeline (8 kt): per-wave 4 loads/STAGE; WAITVM(4) = older buffer
    // complete while the newer 4 stay in flight; bare s_barrier, no drain.
    // (R18 structure — measured 44.8us; R19's 3-buffer variant regressed.)
    STAGE(0, 0)
    STAGE(1, 1)
    for (int kt = 0; kt < 4; kt += 2) {
        WAITVM(4); BAR();         // buf0 ready
        COMPUTE(0)
        BAR();                    // all waves done reading buf0
        STAGE(0, kt + 2)
        WAITVM(4); BAR();         // buf1 ready
        COMPUTE(1)
        BAR();
        STAGE(1, kt + 3)
    }
    WAITVM(4); BAR();
    COMPUTE(0)                    // kt 4
    BAR();
    STAGE(0, 6)
    WAITVM(4); BAR();
    COMPUTE(1)                    // kt 5
    BAR();
    STAGE(1, 7)
    WAITVM(4); BAR();
    COMPUTE(0)                    // kt 6
    WAITVM(0); BAR();
    COMPUTE(1)                    // kt 7
#undef STAGE
#undef COMPUTE

    // Epilogue. 32x32 C/D layout (m74/m101-verified, dtype-independent):
    //   col = lane&31, row = (reg&3) + 8*(reg>>2) + 4*(lane>>5)
    bool offd = (bi != bj);
    int lc[2], gcol[2];
#pragma unroll
    for (int j = 0; j < 2; ++j) {
        gcol[j] = colBase + wn * 64 + j * 32 + l31;
        lc[j] = labels[gcol[j] & (BHALF - 1)];   // 16KB table, cache-hot
    }

    float colD[2] = {0.f, 0.f}, colN[2] = {0.f, 0.f};
#pragma unroll
    for (int i = 0; i < 2; ++i) {
        // D/N fused: v[0..15] = den partials, v[16..31] = nom partials.
        // Peak live = 32 floats — fits the 64-VGPR budget (R18).
        float v[32];
#pragma unroll
        for (int reg = 0; reg < 16; ++reg) {
            int rowIn = (reg & 3) + 8 * (reg >> 2) + 4 * hk;
            int grow = rowBase + wm * 64 + i * 32 + rowIn;
            int labr = labels[grow & (BHALF - 1)];
            float rD = 0.f, rN = 0.f;
#pragma unroll
            for (int j = 0; j < 2; ++j) {
                float e = fexp2(acc[i][j][reg] * EXP_SCALE4);
                if (grow == gcol[j]) e = 0.f;   // diag (only when bi==bj)
                bool m = (lc[j] == labr);
                rD += e; if (m) rN += e;
                colD[j] += e; if (m) colN[j] += e;
            }
            v[reg] = rD;
            v[16 + reg] = rN;
        }
        // Packed butterfly over 32 fused elements across the 32 lanes of
        // this half; afterwards lane l31 holds: l31<16 -> D[reg=l31],
        // l31>=16 -> N[reg=l31-16].
#pragma unroll
        for (int step = 0; step < 5; ++step) {
            const int m = 16 >> step;         // 16,8,4,2,1
            const int h = 16 >> step;
            bool up = (l31 & m) != 0;
#pragma unroll
            for (int k = 0; k < h; ++k) {
                float sV = up ? v[k] : v[k + h];
                float kV = up ? v[k + h] : v[k];
                v[k] = kV + __shfl_xor(sV, m, 64);
            }
        }
        {
            // one device-scope atomic per lane (R0-proven cheap);
            // lanes 0-15 carry den, 16-31 carry nom for reg = l31&15
            int reg = l31 & 15;
            int grow = rowBase + wm * 64 + i * 32 +
                       ((reg & 3) + 8 * (reg >> 2) + 4 * hk);
            float* cell = (l31 & 16) ? &nomden[grow].x    // nom
                                     : &nomden[grow].y;   // den
            atomicAdd(cell, v[0]);
        }
    }
    if (offd) {
        // col sums: fold across the two lane-halves, half 0 scatters
#pragma unroll
        for (int j = 0; j < 2; ++j) {
            float cd = colD[j] + __shfl_xor(colD[j], 32, 64);
            float cn = colN[j] + __shfl_xor(colN[j], 32, 64);
            if (hk == 0) {
                atomicAdd(&nomden[gcol[j]].x, cn);
                atomicAdd(&nomden[gcol[j]].y, cd);
            }
        }
    }

    // Fused finalize: __syncthreads drains vmcnt (all this block's
    // atomics complete at the coherence point), then one ACQ_REL
    // agent-scope counter inc; the block seeing prev==NBLK-1 knows ALL
    // blocks' atomics are complete (each inc is after its own drain).
    // No wbl2 anywhere: every cross-block datum was written atomically.
    __syncthreads();
    __shared__ int lastFlag;
    if (tid == 0) {
        unsigned prev = __hip_atomic_fetch_add(
            counter, 1u, __ATOMIC_ACQ_REL, __HIP_MEMORY_SCOPE_AGENT);
        lastFlag = (prev == NBLK - 1);
    }
    __syncthreads();
    if (lastFlag) {
        float s = 0.f;
        for (int r = tid; r < N2; r += 256) {   // coalesced 8B/lane
            unsigned long long pv = __hip_atomic_load(
                (const unsigned long long*)&nomden[r],
                __ATOMIC_RELAXED, __HIP_MEMORY_SCOPE_AGENT);
            float2 p = __builtin_bit_cast(float2, pv);
            s += __logf(p.y) - __logf(p.x);     // -log(nom/den)
        }
#pragma unroll
        for (int m = 1; m <= 32; m <<= 1) s += __shfl_xor(s, m, 64);
        __shared__ float red[4];
        if ((tid & 63) == 0) red[tid >> 6] = s;
        __syncthreads();
        if (tid == 0)
            out[0] = (red[0] + red[1] + red[2] + red[3]) / (float)N2;
    }
}

extern "C" void kernel_launch(void* const* d_in, const int* in_sizes, int n_in,
                              void* d_out, int out_size, void* d_ws, size_t ws_size,
                              hipStream_t stream) {
    const float* emb_i = (const float*)d_in[0];
    const float* emb_j = (const float*)d_in[1];
    const int* labels  = (const int*)d_in[2];
    float* out = (float*)d_out;

    char* ws = (char*)d_ws;
    u8* reps        = (u8*)ws;                              // 8192*512 = 4 MB
    float2* nomden  = (float2*)(ws + (size_t)N2 * DKB);     // 64 KB
    unsigned* counter = (unsigned*)(ws + (size_t)N2 * DKB + N2 * sizeof(float2));

    normalize_kernel<<<2048, 256, 0, stream>>>(emb_i, emb_j, (u16*)reps,
                                               (float*)nomden, counter, out);
    gemm_loss_kernel<<<NBLK, 256, 0, stream>>>(reps, labels, nomden,
                                               counter, out);
}

// Round 5
// 122.204 us; speedup vs baseline: 1.2610x; 1.2610x over previous
//
#include <hip/hip_runtime.h>
#include <hip/hip_bf16.h>
#include <hip/hip_fp8.h>

// TextualContrastiveLoss: B=4096, D=1024, NUM_CLASSES=100, T=0.5
//   z = l2norm(emb); reps = [z_i; z_j] (8192x1024)
//   sim = reps @ reps^T; e = exp(sim/T) with diag excluded
//   loss = mean_n( log(sum_m e) - log(sum_{m: lab match} e) )
//
// R11 MX mfma_scale_32x32x64 fp8: 71. R12 raw s_barrier+vmcnt: 63.5.
// R15: XCD remap. R16: MX-FP4. R17: deterministic parts stores.
// R18: spill-free fused D/N butterfly epilogue, undef-high fp4 ops,
//      raw v_exp_f32: gemm 44.8us / total 124.2 == CHAMPION.
// R19 FAILED: 3-buffer pipeline -> 3 blocks/CU -> gemm 60.5.
//      TLP > prefetch depth here; occupancy is the binding resource.
// R20 FAILED: fused finalize (last-block counter) + direct atomic
//      epilogue -> gemm 81. Last-block tail (~10us) + unexplained
//      uniform slowdown. Finalize-fusion axis CLOSED (R14/R19/R20).
// R21: revert to R18/R2 champion exactly; drop s_setprio from the
//      K-loop (m190: setprio is null-to-NEGATIVE on barrier-lockstep
//      multi-wave GEMM; it entered R18 un-isolated). Occupancy axis
//      closed by arithmetic: 60 VGPR + 64 AGPR = 124/128 at 4w/SIMD.

#define BHALF 4096
#define N2 8192
#define DK 1024               // elements per row
#define DKB 512               // fp4: bytes per row
#define TILE 128
#define BKB 64                // K bytes staged per kt = 128 elems (8 kt)
#define NTILE 64              // 8192/128
#define NBLK 2080             // 64*65/2 upper-tri tiles = 8 * 260

typedef __attribute__((ext_vector_type(16))) float f32x16;
typedef __attribute__((ext_vector_type(4))) int v4i;
typedef __attribute__((ext_vector_type(8))) int v8i;
typedef unsigned char u8;
typedef unsigned short u16;

// exp(s/0.5) with q = 32*z: sim = acc/1024 -> exp2(acc * 2*log2(e)/1024)
#define EXP_SCALE4 0.0028177637517362566f
#define UNIT_SCALE 0x7f7f7f7f    // E8M0 127 = 2^0 in every byte

// raw barrier / waitcnt — no compiler-inserted vmcnt(0) drain
#define WAITVM(n) asm volatile("s_waitcnt vmcnt(" #n ")" ::: "memory")
#define BAR()     asm volatile("s_barrier" ::: "memory")

// bare v_exp_f32 (2^x); input range here is [-2.9, 2.9] so no denormal
// fixup needed. s_nop covers the TRANS->VALU hazard across the asm edge.
static __device__ __forceinline__ float fexp2(float x) {
    float r;
    asm("v_exp_f32 %0, %1\n\ts_nop 1" : "=v"(r) : "v"(x));
    return r;
}

// float -> fp4 e2m1 nibble, RNE on the e2m1 grid {0,.5,1,1.5,2,3,4,6}
static __device__ __forceinline__ unsigned nib4(float x) {
    unsigned s = (__builtin_bit_cast(unsigned, x) >> 31) << 3;
    float a = fminf(fabsf(x), 6.0f);
    unsigned c;
    if (a < 2.0f)      c = (unsigned)lrintf(a * 2.0f);      // 0,.5..2
    else if (a < 4.0f) c = (unsigned)lrintf(a) + 2u;        // 2,3,4
    else               c = (a < 5.0f) ? 6u : 7u;            // 4 / 6
    return s | c;
}

__global__ __launch_bounds__(256) void normalize_kernel(
    const float* __restrict__ emb_i, const float* __restrict__ emb_j,
    u16* __restrict__ reps, float* __restrict__ out) {
    // one wave per row: 2048 blocks x 4 waves; 16 floats/lane
    int idx = blockIdx.x * 256 + threadIdx.x;
    if (idx == 0) out[0] = 0.0f;
    int r = blockIdx.x * 4 + (threadIdx.x >> 6);     // 0..8191
    int lane = threadIdx.x & 63;
    const float* src = (r < BHALF) ? (emb_i + (size_t)r * DK)
                                   : (emb_j + (size_t)(r - BHALF) * DK);
    const float4* srcv = (const float4*)src;         // 256 float4 per row
    float4 v[4];
    float s = 0.f;
#pragma unroll
    for (int k = 0; k < 4; ++k) {
        v[k] = srcv[k * 64 + lane];
        s += v[k].x * v[k].x + v[k].y * v[k].y +
             v[k].z * v[k].z + v[k].w * v[k].w;
    }
#pragma unroll
    for (int m = 1; m <= 32; m <<= 1) s += __shfl_xor(s, m, 64);
    float scale = 32.0f / fmaxf(sqrtf(s), 1e-12f);   // q = 32 * z
    u16* dst = reps + (size_t)r * 256;               // 256 u16 per row
#pragma unroll
    for (int k = 0; k < 4; ++k) {
        unsigned p = nib4(v[k].x * scale) |
                     (nib4(v[k].y * scale) << 4) |
                     (nib4(v[k].z * scale) << 8) |
                     (nib4(v[k].w * scale) << 12);
        dst[k * 64 + lane] = (u16)p;                 // even elem = low nibble
    }
}

__global__ __launch_bounds__(256, 4) void gemm_loss_kernel(
    const u8* __restrict__ reps, const int* __restrict__ labels,
    float2* __restrict__ parts) {
    // Double-buffered fp4 tiles: 2 x (A 8KB + B 8KB) = 32 KB.
    // Staged rows are 64 B = 4 x 16B blocks = 128 elems. Swizzle: LDS
    // slot (row, b) holds global block b ^ swz(row), swz(r)=(r^(r>>2))&3.
    __shared__ __align__(16) u8 A_s[2][TILE * BKB];
    __shared__ __align__(16) u8 B_s[2][TILE * BKB];
    // cross-wave partial fold: [row=0,col=1][offset]{.x=nom,.y=den}
    __shared__ float2 red2[2][128];

    // XCD-contiguous remap (R15): each mod-8 class walks 260 contiguous
    // tri-indices for L2 reuse.
    int g = blockIdx.x;
    int rem = (g & 7) * 260 + (g >> 3);
    int bi = 0;
    while (rem >= NTILE - bi) { rem -= NTILE - bi; ++bi; }
    int bj = bi + rem;
    int rowBase = bi * TILE;
    int colBase = bj * TILE;

    int tid = threadIdx.x;
    int w = tid >> 6;             // wave 0..3 -> 2x2 of 64x64 subtiles
    int lane = tid & 63;
    int wm = w >> 1, wn = w & 1;
    int hk = lane >> 5;           // lane half: K-half within a 64-K MFMA
    int l31 = lane & 31;

    f32x16 acc[2][2];
#pragma unroll
    for (int i = 0; i < 2; ++i)
#pragma unroll
        for (int j = 0; j < 2; ++j)
#pragma unroll
            for (int r = 0; r < 16; ++r) acc[i][j][r] = 0.0f;

    // staging: 1KB chunk = 16 rows x 64 B; lane l -> LDS (row l>>2,
    // block l&3); fetches global block (l&3)^swz(srow)
    int srow = lane >> 2;
    int sbg = (lane & 3) ^ ((srow ^ (srow >> 2)) & 3);
    const u8* gA = reps + (size_t)(rowBase + w * 32 + srow) * DKB + sbg * 16;
    const u8* gB = reps + (size_t)(colBase + w * 32 + srow) * DKB + sbg * 16;

    // fragment reads: per kt the 64B row covers 128 elems = 2 MFMA
    // K-steps of 64; lane holds elems [ks*64+32*hk, +32) = 16 B at
    // global block (ks*2+hk) -> one b128 per fragment.
    int rswz = (l31 ^ (l31 >> 2)) & 3;
    unsigned aOff[2][2], bOff[2][2];   // [i][ks]
#pragma unroll
    for (int i = 0; i < 2; ++i) {
#pragma unroll
        for (int ks = 0; ks < 2; ++ks) {
            int ra = (wm * 64 + i * 32 + l31) * BKB;
            aOff[i][ks] = ra + (((ks * 2 + hk) ^ rswz) << 4);
            int rb = (wn * 64 + i * 32 + l31) * BKB;
            bOff[i][ks] = rb + (((ks * 2 + hk) ^ rswz) << 4);
        }
    }

#define STAGE(buf, kt)                                                       \
    {                                                                        \
        _Pragma("unroll")                                                    \
        for (int c = 0; c < 2; ++c) {                                        \
            int chunk = 2 * w + c;                                           \
            __builtin_amdgcn_global_load_lds(                                \
                (const __attribute__((address_space(1))) void*)              \
                    (gA + (size_t)c * 16 * DKB + (kt) * BKB),                \
                (__attribute__((address_space(3))) void*)                    \
                    &A_s[buf][chunk * 1024], 16, 0, 0);                      \
            __builtin_amdgcn_global_load_lds(                                \
                (const __attribute__((address_space(1))) void*)              \
                    (gB + (size_t)c * 16 * DKB + (kt) * BKB),                \
                (__attribute__((address_space(3))) void*)                    \
                    &B_s[buf][chunk * 1024], 16, 0, 0);                      \
        }                                                                    \
    }
    // Per kt: 2 K-steps x 4 MFMAs; fp4 fmt (cbsz=4, blgp=4) reads only
    // the LOW 4 regs of each 8-reg operand — leave the high half undef
    // (no v_mov duplication). No setprio: lockstep 4-wave GEMM (m190).
#define COMPUTE(buf)                                                         \
    {                                                                        \
        _Pragma("unroll")                                                    \
        for (int ks = 0; ks < 2; ++ks) {                                     \
            v8i aF[2], bF[2];                                                \
            _Pragma("unroll")                                                \
            for (int i = 0; i < 2; ++i) {                                    \
                v4i a4 = *(const v4i*)&A_s[buf][aOff[i][ks]];                \
                aF[i] = __builtin_shufflevector(a4, a4, 0,1,2,3,-1,-1,-1,-1);\
                v4i b4 = *(const v4i*)&B_s[buf][bOff[i][ks]];                \
                bF[i] = __builtin_shufflevector(b4, b4, 0,1,2,3,-1,-1,-1,-1);\
            }                                                                \
            _Pragma("unroll")                                                \
            for (int i = 0; i < 2; ++i)                                      \
                _Pragma("unroll")                                            \
                for (int j = 0; j < 2; ++j)                                  \
                    acc[i][j] =                                              \
                        __builtin_amdgcn_mfma_scale_f32_32x32x64_f8f6f4(     \
                            aF[i], bF[j], acc[i][j], 4, 4,                   \
                            0, UNIT_SCALE, 0, UNIT_SCALE);                   \
        }                                                                    \
    }

    // Pipeline (8 kt): per-wave 4 loads/STAGE; WAITVM(4) = older buffer
    // complete while the newer 4 stay in flight; bare s_barrier, no drain.
    // (R18 structure — 44.8us measured; R19 3-buffer variant regressed.)
    STAGE(0, 0)
    STAGE(1, 1)
    for (int kt = 0; kt < 4; kt += 2) {
        WAITVM(4); BAR();         // buf0 ready
        COMPUTE(0)
        BAR();                    // all waves done reading buf0
        STAGE(0, kt + 2)
        WAITVM(4); BAR();         // buf1 ready
        COMPUTE(1)
        BAR();
        STAGE(1, kt + 3)
    }
    WAITVM(4); BAR();
    COMPUTE(0)                    // kt 4
    BAR();
    STAGE(0, 6)
    WAITVM(4); BAR();
    COMPUTE(1)                    // kt 5
    BAR();
    STAGE(1, 7)
    WAITVM(4); BAR();
    COMPUTE(0)                    // kt 6
    WAITVM(0); BAR();
    COMPUTE(1)                    // kt 7
#undef STAGE
#undef COMPUTE

    // Epilogue. 32x32 C/D layout (m74/m101-verified, dtype-independent):
    //   col = lane&31, row = (reg&3) + 8*(reg>>2) + 4*(lane>>5)
    bool offd = (bi != bj);
    int lc[2], gcol[2];
#pragma unroll
    for (int j = 0; j < 2; ++j) {
        gcol[j] = colBase + wn * 64 + j * 32 + l31;
        lc[j] = labels[gcol[j] & (BHALF - 1)];   // 16KB table, cache-hot
    }
    // zero the fold buffer before the per-i reductions
    ((float*)red2)[tid] = 0.0f;
    ((float*)red2)[tid + 256] = 0.0f;
    __syncthreads();

    float colD[2] = {0.f, 0.f}, colN[2] = {0.f, 0.f};
#pragma unroll
    for (int i = 0; i < 2; ++i) {
        // D/N fused: v[0..15] = den partials, v[16..31] = nom partials.
        // Peak live = 32 floats — fits the 64-VGPR budget (R18).
        float v[32];
#pragma unroll
        for (int reg = 0; reg < 16; ++reg) {
            int rowIn = (reg & 3) + 8 * (reg >> 2) + 4 * hk;
            int grow = rowBase + wm * 64 + i * 32 + rowIn;
            int labr = labels[grow & (BHALF - 1)];
            float rD = 0.f, rN = 0.f;
#pragma unroll
            for (int j = 0; j < 2; ++j) {
                float e = fexp2(acc[i][j][reg] * EXP_SCALE4);
                if (grow == gcol[j]) e = 0.f;   // diag (only when bi==bj)
                bool m = (lc[j] == labr);
                rD += e; if (m) rN += e;
                colD[j] += e; if (m) colN[j] += e;
            }
            v[reg] = rD;
            v[16 + reg] = rN;
        }
        // Packed butterfly over 32 fused elements across the 32 lanes of
        // this half; afterwards lane l31 holds: l31<16 -> D[reg=l31],
        // l31>=16 -> N[reg=l31-16].
#pragma unroll
        for (int step = 0; step < 5; ++step) {
            const int m = 16 >> step;         // 16,8,4,2,1
            const int h = 16 >> step;
            bool up = (l31 & m) != 0;
#pragma unroll
            for (int k = 0; k < h; ++k) {
                float sV = up ? v[k] : v[k + h];
                float kV = up ? v[k + h] : v[k];
                v[k] = kV + __shfl_xor(sV, m, 64);
            }
        }
        {
            int reg = l31 & 15;
            int rowOff = wm * 64 + i * 32 +
                         ((reg & 3) + 8 * (reg >> 2) + 4 * hk);
            float* cell = (l31 & 16) ? &red2[0][rowOff].x   // nom
                                     : &red2[0][rowOff].y;  // den
            atomicAdd(cell, v[0]);   // ds_add, 2 lanes/bank = free
        }
    }
    if (offd) {
        // col sums: fold across the two lane-halves, half 0 folds into LDS
#pragma unroll
        for (int j = 0; j < 2; ++j) {
            float cd = colD[j] + __shfl_xor(colD[j], 32, 64);
            float cn = colN[j] + __shfl_xor(colN[j], 32, 64);
            if (hk == 0) {
                int colOff = wn * 64 + j * 32 + l31;
                atomicAdd(&red2[1][colOff].x, cn);
                atomicAdd(&red2[1][colOff].y, cd);
            }
        }
    }
    __syncthreads();
    // parts[s*N2 + row]: slot s = other tile coord; regions are provably
    // disjoint across all 2080 blocks (each cell written exactly once).
    if (tid < 128) {
        parts[(size_t)bj * N2 + rowBase + tid] = red2[0][tid];
    } else if (offd) {
        parts[(size_t)bi * N2 + colBase + tid - 128] = red2[1][tid - 128];
    }
}

__global__ __launch_bounds__(256) void finalize_kernel(
    const float2* __restrict__ parts, float* __restrict__ out) {
    int row = blockIdx.x * 256 + threadIdx.x;   // 32 blocks x 256 = 8192
    int t = threadIdx.x;
    float n = 0.f, d = 0.f;
#pragma unroll 8
    for (int s = 0; s < NTILE; ++s) {           // coalesced 8B/lane per s
        float2 p = parts[(size_t)s * N2 + row];
        n += p.x;
        d += p.y;
    }
    float sv = __logf(d) - __logf(n);           // -log(nom/den)
#pragma unroll
    for (int m = 1; m <= 32; m <<= 1) sv += __shfl_xor(sv, m, 64);
    __shared__ float red[4];
    if ((t & 63) == 0) red[t >> 6] = sv;
    __syncthreads();
    if (t == 0)
        atomicAdd(out, (red[0] + red[1] + red[2] + red[3]) / (float)N2);
}

extern "C" void kernel_launch(void* const* d_in, const int* in_sizes, int n_in,
                              void* d_out, int out_size, void* d_ws, size_t ws_size,
                              hipStream_t stream) {
    const float* emb_i = (const float*)d_in[0];
    const float* emb_j = (const float*)d_in[1];
    const int* labels  = (const int*)d_in[2];
    float* out = (float*)d_out;

    char* ws = (char*)d_ws;
    u8* reps     = (u8*)ws;                                 // 8192*512 = 4 MB
    float2* parts = (float2*)(ws + (size_t)N2 * DKB);       // 64*8192*8 = 4 MB

    normalize_kernel<<<2048, 256, 0, stream>>>(emb_i, emb_j, (u16*)reps, out);
    gemm_loss_kernel<<<NBLK, 256, 0, stream>>>(reps, labels, parts);
    finalize_kernel<<<(N2 + 255) / 256, 256, 0, stream>>>(parts, out);
}